// Round 9
// baseline (614.704 us; speedup 1.0000x reference)
//
#include <hip/hip_runtime.h>
#include <hip/hip_bf16.h>

#define N_NODES 100000
#define E_EDGES 1600000
#define NG 512
#define FIN 7
#define HID 128
#define NBUCK 782          // ceil(N_NODES/128), bucket = 128 consecutive dst nodes
#define NBLK_SC 128        // partition blocks (each owns a contiguous edge chunk)
#define CHUNK 12500        // E_EDGES / NBLK_SC (exact)
#define TLEN (NBUCK * NBLK_SC)   // 100096 table entries
#define PERTHR 98          // ceil(TLEN/1024) elements per scan thread
#define MMX_GRID 782       // ceil(N_NODES/128)

typedef __attribute__((ext_vector_type(8))) short bf16x8;
typedef __attribute__((ext_vector_type(4))) float f32x4;

// bf16 helpers: decode packed pair, encode with RNE
__device__ __forceinline__ float bf_lo(unsigned int u) { return __uint_as_float(u << 16); }
__device__ __forceinline__ float bf_hi(unsigned int u) { return __uint_as_float(u & 0xffff0000u); }
__device__ __forceinline__ unsigned int f2bf_rne(float f) {
    unsigned int x = __float_as_uint(f);
    return (x + 0x7fffu + ((x >> 16) & 1u)) >> 16;   // finite inputs only
}
__device__ __forceinline__ unsigned int pack_bf2(float lo, float hi) {
    return f2bf_rne(lo) | (f2bf_rne(hi) << 16);
}

// ---------------- CSR build (radix partition) ----------------

__global__ __launch_bounds__(256) void k_hist2(const int* __restrict__ eidx,
                                               int* __restrict__ table) {
    __shared__ int h[NBUCK];
    int blk = blockIdx.x, t = threadIdx.x;
    for (int i = t; i < NBUCK; i += 256) h[i] = 0;
    __syncthreads();
    int e0 = blk * CHUNK, e1 = e0 + CHUNK;
    for (int e = e0 + t; e < e1; e += 256)
        atomicAdd(&h[eidx[E_EDGES + e] >> 7], 1);
    __syncthreads();
    for (int i = t; i < NBUCK; i += 256)
        table[i * NBLK_SC + blk] = h[i];
}

// One-kernel exclusive scan of table[TLEN] (+ bucketBase extraction + sentinels)
__global__ __launch_bounds__(1024) void k_scanall(int* __restrict__ table,
                                                  int* __restrict__ bucketBase,
                                                  int* __restrict__ rowptr) {
    __shared__ int s[1024];
    int t = threadIdx.x;
    int i0 = t * PERTHR, i1 = i0 + PERTHR; if (i1 > TLEN) i1 = TLEN;
    int sum = 0;
    for (int i = i0; i < i1; ++i) sum += table[i];
    s[t] = sum; __syncthreads();
    for (int st = 1; st < 1024; st <<= 1) {
        int a = (t >= st) ? s[t - st] : 0;
        __syncthreads();
        s[t] += a;
        __syncthreads();
    }
    int run = s[t] - sum;   // exclusive prefix of this thread's range
    for (int i = i0; i < i1; ++i) {
        int v = table[i];
        table[i] = run;
        if ((i & (NBLK_SC - 1)) == 0) bucketBase[i >> 7] = run;
        run += v;
    }
    if (t == 0) { bucketBase[NBUCK] = E_EDGES; rowptr[N_NODES] = E_EDGES; }
}

__global__ __launch_bounds__(256) void k_scatter2(const int* __restrict__ eidx,
                                                  const int* __restrict__ table,
                                                  unsigned int* __restrict__ ebuf) {
    __shared__ int loff[NBUCK];
    int blk = blockIdx.x, t = threadIdx.x;
    for (int i = t; i < NBUCK; i += 256) loff[i] = table[i * NBLK_SC + blk];
    __syncthreads();
    int e0 = blk * CHUNK, e1 = e0 + CHUNK;
    for (int e = e0 + t; e < e1; e += 256) {
        int s = eidx[e];
        int d = eidx[E_EDGES + e];
        int p = atomicAdd(&loff[d >> 7], 1);
        ebuf[p] = ((unsigned int)(d & 127) << 17) | (unsigned int)s;
    }
}

__global__ __launch_bounds__(256) void k_bucket(const unsigned int* __restrict__ ebuf,
                                                const int* __restrict__ bucketBase,
                                                int* __restrict__ rowptr,
                                                float* __restrict__ dinv,
                                                int* __restrict__ col) {
    __shared__ int scnt[128], soff[128], scur[128];
    int b = blockIdx.x, t = threadIdx.x;
    int bbase = bucketBase[b], bend = bucketBase[b + 1];
    if (t < 128) { scnt[t] = 0; scur[t] = 0; }
    __syncthreads();
    for (int e = bbase + t; e < bend; e += 256) {
        unsigned int rec = ebuf[e];
        atomicAdd(&scnt[rec >> 17], 1);
    }
    __syncthreads();
    if (t < 128) soff[t] = scnt[t];
    __syncthreads();
    for (int st = 1; st < 128; st <<= 1) {
        int a = (t < 128 && t >= st) ? soff[t - st] : 0;
        __syncthreads();
        if (t < 128) soff[t] += a;
        __syncthreads();
    }
    if (t < 128) {
        int ex = soff[t] - scnt[t];
        int node = b * 128 + t;
        if (node < N_NODES) {
            rowptr[node] = bbase + ex;
            dinv[node] = rsqrtf((float)(scnt[t] + 1));   // +1 self-loop
        }
        soff[t] = ex;
    }
    __syncthreads();
    for (int e = bbase + t; e < bend; e += 256) {
        unsigned int rec = ebuf[e];
        int dl = rec >> 17;
        int s = rec & 0x1FFFF;
        int p = bbase + soff[dl] + atomicAdd(&scur[dl], 1);
        col[p] = s;
    }
}

// ---------------- layer 1 aggregation (7-wide, fp32 x) ----------------

__global__ void k_agg7(const float* __restrict__ x, const int* __restrict__ rowptr,
                       const int* __restrict__ col, const float* __restrict__ dinv,
                       float* __restrict__ aggx) {
    int i = blockIdx.x * blockDim.x + threadIdx.x;
    if (i >= N_NODES) return;
    float di = dinv[i];
    float a[FIN];
    #pragma unroll
    for (int f = 0; f < FIN; ++f) a[f] = di * x[i * FIN + f];
    int e0 = rowptr[i], e1 = rowptr[i + 1];
    for (int e = e0; e < e1; ++e) {
        int s = col[e];
        float ds = dinv[s];
        #pragma unroll
        for (int f = 0; f < FIN; ++f) a[f] += ds * x[s * FIN + f];
    }
    #pragma unroll
    for (int f = 0; f < FIN; ++f) aggx[i * FIN + f] = di * a[f];
}

// layer-1 matmul: out = relu(aggx @ W1 + b1) cast to packed bf16
__global__ void k_mm1(const float* __restrict__ aggx, const float* __restrict__ W1,
                      const float* __restrict__ b1, unsigned int* __restrict__ g1) {
    int idx = blockIdx.x * blockDim.x + threadIdx.x;   // N*64 threads
    if (idx >= N_NODES * 64) return;
    int n = idx >> 6, fp = idx & 63;
    int f0 = 2 * fp;
    float acc0 = b1[f0], acc1 = b1[f0 + 1];
    #pragma unroll
    for (int k = 0; k < FIN; ++k) {
        float a = aggx[n * FIN + k];
        acc0 += a * W1[k * HID + f0];
        acc1 += a * W1[k * HID + f0 + 1];
    }
    g1[idx] = pack_bf2(fmaxf(acc0, 0.f), fmaxf(acc1, 0.f));
}

// ---------------- 128-wide aggregation (wave/node, bf16 gather, shfl-batched) --------
// Always writes packed bf16 [N][64]. 8-wide gather unroll for MLP.

__global__ void k_agg128(const unsigned int* __restrict__ g,   // packed bf16 pairs [N][64]
                         unsigned int* __restrict__ oB,
                         const int* __restrict__ rowptr, const int* __restrict__ col,
                         const float* __restrict__ dinv) {
    int wid = (blockIdx.x * blockDim.x + threadIdx.x) >> 6;
    int lane = threadIdx.x & 63;
    if (wid >= N_NODES) return;
    int i = wid;
    float di = dinv[i];
    unsigned int v = g[(size_t)i * 64 + lane];
    float ax = di * bf_lo(v), ay = di * bf_hi(v);
    int e0 = rowptr[i], e1 = rowptr[i + 1];
    for (int base = e0; base < e1; base += 64) {
        int m = e1 - base; if (m > 64) m = 64;
        int sc = 0; float dsv = 0.f;
        if (lane < m) { sc = col[base + lane]; dsv = dinv[sc]; }
        int j = 0;
        for (; j + 7 < m; j += 8) {
            int s0 = __shfl(sc, j),     s1 = __shfl(sc, j + 1);
            int s2 = __shfl(sc, j + 2), s3 = __shfl(sc, j + 3);
            int s4 = __shfl(sc, j + 4), s5 = __shfl(sc, j + 5);
            int s6 = __shfl(sc, j + 6), s7 = __shfl(sc, j + 7);
            float d0 = __shfl(dsv, j),     d1 = __shfl(dsv, j + 1);
            float d2 = __shfl(dsv, j + 2), d3 = __shfl(dsv, j + 3);
            float d4 = __shfl(dsv, j + 4), d5 = __shfl(dsv, j + 5);
            float d6 = __shfl(dsv, j + 6), d7 = __shfl(dsv, j + 7);
            unsigned int u0 = g[(size_t)s0 * 64 + lane];
            unsigned int u1 = g[(size_t)s1 * 64 + lane];
            unsigned int u2 = g[(size_t)s2 * 64 + lane];
            unsigned int u3 = g[(size_t)s3 * 64 + lane];
            unsigned int u4 = g[(size_t)s4 * 64 + lane];
            unsigned int u5 = g[(size_t)s5 * 64 + lane];
            unsigned int u6 = g[(size_t)s6 * 64 + lane];
            unsigned int u7 = g[(size_t)s7 * 64 + lane];
            ax += d0 * bf_lo(u0); ay += d0 * bf_hi(u0);
            ax += d1 * bf_lo(u1); ay += d1 * bf_hi(u1);
            ax += d2 * bf_lo(u2); ay += d2 * bf_hi(u2);
            ax += d3 * bf_lo(u3); ay += d3 * bf_hi(u3);
            ax += d4 * bf_lo(u4); ay += d4 * bf_hi(u4);
            ax += d5 * bf_lo(u5); ay += d5 * bf_hi(u5);
            ax += d6 * bf_lo(u6); ay += d6 * bf_hi(u6);
            ax += d7 * bf_lo(u7); ay += d7 * bf_hi(u7);
        }
        for (; j + 3 < m; j += 4) {
            int s0 = __shfl(sc, j),     s1 = __shfl(sc, j + 1);
            int s2 = __shfl(sc, j + 2), s3 = __shfl(sc, j + 3);
            float d0 = __shfl(dsv, j),     d1 = __shfl(dsv, j + 1);
            float d2 = __shfl(dsv, j + 2), d3 = __shfl(dsv, j + 3);
            unsigned int u0 = g[(size_t)s0 * 64 + lane];
            unsigned int u1 = g[(size_t)s1 * 64 + lane];
            unsigned int u2 = g[(size_t)s2 * 64 + lane];
            unsigned int u3 = g[(size_t)s3 * 64 + lane];
            ax += d0 * bf_lo(u0); ay += d0 * bf_hi(u0);
            ax += d1 * bf_lo(u1); ay += d1 * bf_hi(u1);
            ax += d2 * bf_lo(u2); ay += d2 * bf_hi(u2);
            ax += d3 * bf_lo(u3); ay += d3 * bf_hi(u3);
        }
        for (; j < m; ++j) {
            int s0 = __shfl(sc, j);
            float d0 = __shfl(dsv, j);
            unsigned int u0 = g[(size_t)s0 * 64 + lane];
            ax += d0 * bf_lo(u0); ay += d0 * bf_hi(u0);
        }
    }
    oB[(size_t)i * 64 + lane] = pack_bf2(di * ax, di * ay);
}

// ---------------- MFMA matmul (layers 2,3): g_out = bf16(relu(A @ W + b)) -----------
// Wave: 32 nodes x 128 feats; block: 4 waves = 128 nodes. W staged transposed in LDS.

__global__ __launch_bounds__(256) void k_mmx(const unsigned int* __restrict__ gIn,
                                             const float* __restrict__ W,
                                             const float* __restrict__ bias,
                                             unsigned int* __restrict__ outg) {
    __shared__ unsigned short sbuf[128 * 136];   // 34816 B: WT (stride 136), reused as Cs (stride 132)
    int t = threadIdx.x;
    // stage W transposed as bf16: WT[n*136 + k] = bf16(W[k][n])
    for (int i = t; i < 128 * 128; i += 256) {
        int k = i >> 7, n = i & 127;
        sbuf[n * 136 + k] = (unsigned short)f2bf_rne(W[i]);
    }

    int lane = t & 63, wave = t >> 6;
    int m = lane & 15, quad = lane >> 4;
    int nodeBase = blockIdx.x * 128 + wave * 32;
    const short* gs = (const short*)gIn;

    float bi[8];
    #pragma unroll
    for (int nt = 0; nt < 8; ++nt) bi[nt] = bias[nt * 16 + m];

    f32x4 acc[2][8];
    #pragma unroll
    for (int gi = 0; gi < 2; ++gi)
        #pragma unroll
        for (int nt = 0; nt < 8; ++nt)
            acc[gi][nt] = (f32x4){0.f, 0.f, 0.f, 0.f};

    __syncthreads();

    #pragma unroll
    for (int kc = 0; kc < 4; ++kc) {
        bf16x8 ah[2];
        #pragma unroll
        for (int gi = 0; gi < 2; ++gi) {
            int node = nodeBase + gi * 16 + m;
            bf16x8 h = {0, 0, 0, 0, 0, 0, 0, 0};
            if (node < N_NODES)
                h = *(const bf16x8*)(gs + (size_t)node * 128 + kc * 32 + quad * 8);
            ah[gi] = h;
        }
        #pragma unroll
        for (int nt = 0; nt < 8; ++nt) {
            bf16x8 b = *(const bf16x8*)(sbuf + (nt * 16 + m) * 136 + kc * 32 + quad * 8);
            #pragma unroll
            for (int gi = 0; gi < 2; ++gi)
                acc[gi][nt] = __builtin_amdgcn_mfma_f32_16x16x32_bf16(ah[gi], b, acc[gi][nt], 0, 0, 0);
        }
    }

    __syncthreads();   // all waves done reading WT
    // epilogue: bias+relu+bf16, scatter to Cs[node_local][feat], stride 132
    // C/D layout: col=lane&15 (feat m), row=quad*4+reg (node within 16-group)
    #pragma unroll
    for (int gi = 0; gi < 2; ++gi)
        #pragma unroll
        for (int nt = 0; nt < 8; ++nt)
            #pragma unroll
            for (int r = 0; r < 4; ++r) {
                int nl = wave * 32 + gi * 16 + quad * 4 + r;
                float vv = acc[gi][nt][r] + bi[nt];
                sbuf[nl * 132 + nt * 16 + m] = (unsigned short)f2bf_rne(fmaxf(vv, 0.f));
            }
    __syncthreads();
    // cooperative coalesced store: 4 bf16 (uint2) per iteration
    for (int i = t; i < 128 * 32; i += 256) {
        int nl = i >> 5, p = i & 31;
        int node = blockIdx.x * 128 + nl;
        if (node < N_NODES) {
            uint2 val = *(const uint2*)(sbuf + nl * 132 + p * 4);
            *(uint2*)&outg[(size_t)node * 64 + p * 2] = val;
        }
    }
}

// ------------- head weight folding (block 64) + pooled zero-init (blocks 0-63) -------

__global__ void k_wc(const float* __restrict__ W4, const float* __restrict__ b4,
                     const float* __restrict__ Wlin, const float* __restrict__ blin,
                     float* __restrict__ Wc, float* __restrict__ bc,
                     float* __restrict__ pooled) {
    int t = threadIdx.x;
    if (blockIdx.x < 64) {
        // zero pooled: 64 blocks x 256 threads x 4 floats = 65536 = NG*HID
        float4 z = {0.f, 0.f, 0.f, 0.f};
        *(float4*)&pooled[(blockIdx.x * 256 + t) * 4] = z;
        return;
    }
    int k = t >> 1, o = t & 1;
    float acc = 0.f;
    for (int j = 0; j < HID; ++j) acc += W4[k * HID + j] * Wlin[j * 2 + o];
    Wc[k * 2 + o] = acc;
    if (k == 0) {
        float b = blin[o];
        for (int j = 0; j < HID; ++j) b += b4[j] * Wlin[j * 2 + o];
        bc[o] = b;
    }
}

// ---------------- pool stage 1: per-chunk partial sums (bf16 in, fp32 atomics) -------

__global__ __launch_bounds__(256) void k_poolsum(const unsigned int* __restrict__ aggB,
                                                 const int* __restrict__ batch,
                                                 float* __restrict__ pooled) {
    int wid = (blockIdx.x * blockDim.x + threadIdx.x) >> 6;   // wave id: 16 nodes each
    int lane = threadIdx.x & 63;
    int n0 = wid * 16;
    if (n0 >= N_NODES) return;
    int n1 = n0 + 16; if (n1 > N_NODES) n1 = N_NODES;
    int curg = batch[n0];
    float ax = 0.f, ay = 0.f;
    for (int n = n0; n < n1; ++n) {
        int g = batch[n];
        if (g != curg) {
            atomicAdd(&pooled[curg * HID + 2 * lane], ax);
            atomicAdd(&pooled[curg * HID + 2 * lane + 1], ay);
            ax = 0.f; ay = 0.f; curg = g;
        }
        unsigned int u = aggB[(size_t)n * 64 + lane];
        ax += bf_lo(u); ay += bf_hi(u);
    }
    atomicAdd(&pooled[curg * HID + 2 * lane], ax);
    atomicAdd(&pooled[curg * HID + 2 * lane + 1], ay);
}

// ---------------- head: mean + fused W4*Wlin linear ----------------

__global__ void k_head(const float* __restrict__ pooled, const int* __restrict__ batch,
                       const float* __restrict__ Wc, const float* __restrict__ bc,
                       const float* __restrict__ blin, float* __restrict__ out) {
    int wid = (blockIdx.x * blockDim.x + threadIdx.x) >> 6;
    int lane = threadIdx.x & 63;
    if (wid >= NG) return;
    int g = wid;
    int lo = 0, hi = N_NODES;
    while (lo < hi) { int mid = (lo + hi) >> 1; if (batch[mid] < g) lo = mid + 1; else hi = mid; }
    int start = lo;
    hi = N_NODES;
    while (lo < hi) { int mid = (lo + hi) >> 1; if (batch[mid] < g + 1) lo = mid + 1; else hi = mid; }
    int cnt = lo - start;
    float invc = (cnt > 0) ? 1.0f / (float)cnt : 0.f;
    float px = pooled[g * HID + 2 * lane] * invc;
    float py = pooled[g * HID + 2 * lane + 1] * invc;

    #pragma unroll
    for (int o = 0; o < 2; ++o) {
        float v = px * Wc[(2 * lane) * 2 + o] + py * Wc[(2 * lane + 1) * 2 + o];
        #pragma unroll
        for (int s = 32; s > 0; s >>= 1) v += __shfl_down(v, s);
        if (lane == 0) out[g * 2 + o] = (cnt > 0) ? (v + bc[o]) : blin[o];
    }
}

// ---------------- launcher ----------------

extern "C" void kernel_launch(void* const* d_in, const int* in_sizes, int n_in,
                              void* d_out, int out_size, void* d_ws, size_t ws_size,
                              hipStream_t stream) {
    const float* x    = (const float*)d_in[0];
    const int*   eidx = (const int*)d_in[1];
    const int*   batch= (const int*)d_in[2];
    const float* W1   = (const float*)d_in[3];
    const float* b1   = (const float*)d_in[4];
    const float* W2   = (const float*)d_in[5];
    const float* b2   = (const float*)d_in[6];
    const float* W3   = (const float*)d_in[7];
    const float* b3   = (const float*)d_in[8];
    const float* W4   = (const float*)d_in[9];
    const float* b4   = (const float*)d_in[10];
    const float* Wlin = (const float*)d_in[11];
    const float* blin = (const float*)d_in[12];
    float* out = (float*)d_out;

    // workspace carve-up (256B aligned)
    char* ws = (char*)d_ws;
    size_t off = 0;
    auto carve = [&](size_t bytes) { char* p = ws + off; off = (off + bytes + 255) & ~(size_t)255; return p; };
    int*   rowptr    = (int*)carve((size_t)(N_NODES + 1) * 4);
    float* dinv      = (float*)carve((size_t)N_NODES * 4);
    int*   col       = (int*)carve((size_t)E_EDGES * 4);
    unsigned int* ebuf = (unsigned int*)carve((size_t)E_EDGES * 4);
    int*   table     = (int*)carve((size_t)TLEN * 4);
    int*   bucketBase= (int*)carve((size_t)(NBUCK + 1) * 4);
    float* aggx      = (float*)carve((size_t)N_NODES * FIN * 4);
    unsigned int* gA = (unsigned int*)carve((size_t)N_NODES * 64 * 4);   // 25.6 MB bf16 buffer
    unsigned int* gB = (unsigned int*)carve((size_t)N_NODES * 64 * 4);   // 25.6 MB bf16 buffer
    float* pooled    = (float*)carve((size_t)NG * HID * 4);
    float* Wc        = (float*)carve((size_t)HID * 2 * 4);
    float* bc        = (float*)carve(2 * 4);
    (void)ws_size; (void)n_in; (void)in_sizes; (void)out_size;

    const int BLK = 256;
    int gridN = (N_NODES + BLK - 1) / BLK;
    int gridAgg = (N_NODES * 64 + BLK - 1) / BLK;
    int gridMM1 = (N_NODES * 64 + BLK - 1) / BLK;
    int gridPS = ((N_NODES + 15) / 16 * 64 + BLK - 1) / BLK;
    int gridHead = (NG * 64 + BLK - 1) / BLK;

    // CSR build (radix partition: hist -> scan -> scatter -> bucket finalize)
    k_hist2<<<NBLK_SC, BLK, 0, stream>>>(eidx, table);
    k_scanall<<<1, 1024, 0, stream>>>(table, bucketBase, rowptr);
    k_scatter2<<<NBLK_SC, BLK, 0, stream>>>(eidx, table, ebuf);
    k_bucket<<<NBUCK, BLK, 0, stream>>>(ebuf, bucketBase, rowptr, dinv, col);

    // head weight folding + pooled zero-init (independent of graph pipeline)
    k_wc<<<65, 256, 0, stream>>>(W4, b4, Wlin, blin, Wc, bc, pooled);

    // layer 1: g1 = bf16(relu((A' x) W1 + b1))
    k_agg7<<<gridN, BLK, 0, stream>>>(x, rowptr, col, dinv, aggx);
    k_mm1<<<gridMM1, BLK, 0, stream>>>(aggx, W1, b1, gA);

    // layer 2: a2 = bf16(A' g1) -> MFMA mm -> g2
    k_agg128<<<gridAgg, BLK, 0, stream>>>(gA, gB, rowptr, col, dinv);
    k_mmx<<<MMX_GRID, BLK, 0, stream>>>(gB, W2, b2, gA);
    // layer 3: a3 = bf16(A' g2) -> MFMA mm -> g3
    k_agg128<<<gridAgg, BLK, 0, stream>>>(gA, gB, rowptr, col, dinv);
    k_mmx<<<MMX_GRID, BLK, 0, stream>>>(gB, W3, b3, gA);
    // layer 4: aggregation only (W4 folded into head), bf16 out
    k_agg128<<<gridAgg, BLK, 0, stream>>>(gA, gB, rowptr, col, dinv);

    // pool + head
    k_poolsum<<<gridPS, BLK, 0, stream>>>(gB, batch, pooled);
    k_head<<<gridHead, BLK, 0, stream>>>(pooled, batch, Wc, bc, blin, out);
}

// Round 10
// 459.942 us; speedup vs baseline: 1.3365x; 1.3365x over previous
//
#include <hip/hip_runtime.h>
#include <hip/hip_bf16.h>

#define N_NODES 100000
#define E_EDGES 1600000
#define NG 512
#define FIN 7
#define HID 128
#define NBUCK 782          // ceil(N_NODES/128), bucket = 128 consecutive dst nodes
#define NBLK_SC 128        // partition blocks (each owns a contiguous edge chunk)
#define CHUNK 12500        // E_EDGES / NBLK_SC (exact)
#define TLEN (NBUCK * NBLK_SC)   // 100096 table entries
#define NCH 98             // ceil(TLEN/1024) scan chunks
#define MMX_GRID 782       // ceil(N_NODES/128)

typedef __attribute__((ext_vector_type(8))) short bf16x8;
typedef __attribute__((ext_vector_type(4))) float f32x4;

// bf16 helpers: decode packed pair, encode with RNE
__device__ __forceinline__ float bf_lo(unsigned int u) { return __uint_as_float(u << 16); }
__device__ __forceinline__ float bf_hi(unsigned int u) { return __uint_as_float(u & 0xffff0000u); }
__device__ __forceinline__ unsigned int f2bf_rne(float f) {
    unsigned int x = __float_as_uint(f);
    return (x + 0x7fffu + ((x >> 16) & 1u)) >> 16;   // finite inputs only
}
__device__ __forceinline__ unsigned int pack_bf2(float lo, float hi) {
    return f2bf_rne(lo) | (f2bf_rne(hi) << 16);
}

// ---------------- CSR build (radix partition) ----------------

__global__ __launch_bounds__(256) void k_hist2(const int* __restrict__ eidx,
                                               int* __restrict__ table) {
    __shared__ int h[NBUCK];
    int blk = blockIdx.x, t = threadIdx.x;
    for (int i = t; i < NBUCK; i += 256) h[i] = 0;
    __syncthreads();
    int e0 = blk * CHUNK, e1 = e0 + CHUNK;
    for (int e = e0 + t; e < e1; e += 256)
        atomicAdd(&h[eidx[E_EDGES + e] >> 7], 1);
    __syncthreads();
    for (int i = t; i < NBUCK; i += 256)
        table[i * NBLK_SC + blk] = h[i];
}

__global__ void k_blocksum(const int* __restrict__ table, int* __restrict__ partial) {
    __shared__ int s[256];
    int b = blockIdx.x, t = threadIdx.x;
    int base = b * 1024;
    int sum = 0;
    for (int i = t; i < 1024; i += 256) {
        int idx = base + i;
        sum += (idx < TLEN) ? table[idx] : 0;
    }
    s[t] = sum; __syncthreads();
    for (int st = 128; st > 0; st >>= 1) {
        if (t < st) s[t] += s[t + st];
        __syncthreads();
    }
    if (t == 0) partial[b] = s[0];
}

__global__ void k_scan_blk(int* __restrict__ partial, int* __restrict__ bucketBase,
                           int* __restrict__ rowptr) {
    if (threadIdx.x == 0 && blockIdx.x == 0) {
        int run = 0;
        for (int i = 0; i < NCH; ++i) { int v = partial[i]; partial[i] = run; run += v; }
        bucketBase[NBUCK] = E_EDGES;
        rowptr[N_NODES] = E_EDGES;
    }
}

__global__ void k_scan_final(int* __restrict__ table, const int* __restrict__ partial,
                             int* __restrict__ bucketBase) {
    __shared__ int s[1024];
    int b = blockIdx.x, t = threadIdx.x;
    int idx = b * 1024 + t;
    int v = (idx < TLEN) ? table[idx] : 0;
    s[t] = v; __syncthreads();
    for (int st = 1; st < 1024; st <<= 1) {
        int add = (t >= st) ? s[t - st] : 0;
        __syncthreads();
        s[t] += add;
        __syncthreads();
    }
    if (idx < TLEN) {
        int ex = partial[b] + s[t] - v;   // exclusive
        table[idx] = ex;
        if ((idx & (NBLK_SC - 1)) == 0) bucketBase[idx >> 7] = ex;
    }
}

__global__ __launch_bounds__(256) void k_scatter2(const int* __restrict__ eidx,
                                                  const int* __restrict__ table,
                                                  unsigned int* __restrict__ ebuf) {
    __shared__ int loff[NBUCK];
    int blk = blockIdx.x, t = threadIdx.x;
    for (int i = t; i < NBUCK; i += 256) loff[i] = table[i * NBLK_SC + blk];
    __syncthreads();
    int e0 = blk * CHUNK, e1 = e0 + CHUNK;
    for (int e = e0 + t; e < e1; e += 256) {
        int s = eidx[e];
        int d = eidx[E_EDGES + e];
        int p = atomicAdd(&loff[d >> 7], 1);
        ebuf[p] = ((unsigned int)(d & 127) << 17) | (unsigned int)s;
    }
}

__global__ __launch_bounds__(256) void k_bucket(const unsigned int* __restrict__ ebuf,
                                                const int* __restrict__ bucketBase,
                                                int* __restrict__ rowptr,
                                                float* __restrict__ dinv,
                                                int* __restrict__ col) {
    __shared__ int scnt[128], soff[128], scur[128];
    int b = blockIdx.x, t = threadIdx.x;
    int bbase = bucketBase[b], bend = bucketBase[b + 1];
    if (t < 128) { scnt[t] = 0; scur[t] = 0; }
    __syncthreads();
    for (int e = bbase + t; e < bend; e += 256) {
        unsigned int rec = ebuf[e];
        atomicAdd(&scnt[rec >> 17], 1);
    }
    __syncthreads();
    if (t < 128) soff[t] = scnt[t];
    __syncthreads();
    for (int st = 1; st < 128; st <<= 1) {
        int a = (t < 128 && t >= st) ? soff[t - st] : 0;
        __syncthreads();
        if (t < 128) soff[t] += a;
        __syncthreads();
    }
    if (t < 128) {
        int ex = soff[t] - scnt[t];
        int node = b * 128 + t;
        if (node < N_NODES) {
            rowptr[node] = bbase + ex;
            dinv[node] = rsqrtf((float)(scnt[t] + 1));   // +1 self-loop
        }
        soff[t] = ex;
    }
    __syncthreads();
    for (int e = bbase + t; e < bend; e += 256) {
        unsigned int rec = ebuf[e];
        int dl = rec >> 17;
        int s = rec & 0x1FFFF;
        int p = bbase + soff[dl] + atomicAdd(&scur[dl], 1);
        col[p] = s;
    }
}

// ---------------- layer 1 aggregation (7-wide, fp32 x) ----------------

__global__ void k_agg7(const float* __restrict__ x, const int* __restrict__ rowptr,
                       const int* __restrict__ col, const float* __restrict__ dinv,
                       float* __restrict__ aggx) {
    int i = blockIdx.x * blockDim.x + threadIdx.x;
    if (i >= N_NODES) return;
    float di = dinv[i];
    float a[FIN];
    #pragma unroll
    for (int f = 0; f < FIN; ++f) a[f] = di * x[i * FIN + f];
    int e0 = rowptr[i], e1 = rowptr[i + 1];
    for (int e = e0; e < e1; ++e) {
        int s = col[e];
        float ds = dinv[s];
        #pragma unroll
        for (int f = 0; f < FIN; ++f) a[f] += ds * x[s * FIN + f];
    }
    #pragma unroll
    for (int f = 0; f < FIN; ++f) aggx[i * FIN + f] = di * a[f];
}

// layer-1 matmul: out = relu(aggx @ W1 + b1) cast to packed bf16
__global__ void k_mm1(const float* __restrict__ aggx, const float* __restrict__ W1,
                      const float* __restrict__ b1, unsigned int* __restrict__ g1) {
    int idx = blockIdx.x * blockDim.x + threadIdx.x;   // N*64 threads
    if (idx >= N_NODES * 64) return;
    int n = idx >> 6, fp = idx & 63;
    int f0 = 2 * fp;
    float acc0 = b1[f0], acc1 = b1[f0 + 1];
    #pragma unroll
    for (int k = 0; k < FIN; ++k) {
        float a = aggx[n * FIN + k];
        acc0 += a * W1[k * HID + f0];
        acc1 += a * W1[k * HID + f0 + 1];
    }
    g1[idx] = pack_bf2(fmaxf(acc0, 0.f), fmaxf(acc1, 0.f));
}

// ---------------- 128-wide aggregation (wave/node, bf16 gather, shfl-batched) --------
// Always writes packed bf16 [N][64]. 8-wide gather unroll for MLP.

__global__ void k_agg128(const unsigned int* __restrict__ g,   // packed bf16 pairs [N][64]
                         unsigned int* __restrict__ oB,
                         const int* __restrict__ rowptr, const int* __restrict__ col,
                         const float* __restrict__ dinv) {
    int wid = (blockIdx.x * blockDim.x + threadIdx.x) >> 6;
    int lane = threadIdx.x & 63;
    if (wid >= N_NODES) return;
    int i = wid;
    float di = dinv[i];
    unsigned int v = g[(size_t)i * 64 + lane];
    float ax = di * bf_lo(v), ay = di * bf_hi(v);
    int e0 = rowptr[i], e1 = rowptr[i + 1];
    for (int base = e0; base < e1; base += 64) {
        int m = e1 - base; if (m > 64) m = 64;
        int sc = 0; float dsv = 0.f;
        if (lane < m) { sc = col[base + lane]; dsv = dinv[sc]; }
        int j = 0;
        for (; j + 7 < m; j += 8) {
            int s0 = __shfl(sc, j),     s1 = __shfl(sc, j + 1);
            int s2 = __shfl(sc, j + 2), s3 = __shfl(sc, j + 3);
            int s4 = __shfl(sc, j + 4), s5 = __shfl(sc, j + 5);
            int s6 = __shfl(sc, j + 6), s7 = __shfl(sc, j + 7);
            float d0 = __shfl(dsv, j),     d1 = __shfl(dsv, j + 1);
            float d2 = __shfl(dsv, j + 2), d3 = __shfl(dsv, j + 3);
            float d4 = __shfl(dsv, j + 4), d5 = __shfl(dsv, j + 5);
            float d6 = __shfl(dsv, j + 6), d7 = __shfl(dsv, j + 7);
            unsigned int u0 = g[(size_t)s0 * 64 + lane];
            unsigned int u1 = g[(size_t)s1 * 64 + lane];
            unsigned int u2 = g[(size_t)s2 * 64 + lane];
            unsigned int u3 = g[(size_t)s3 * 64 + lane];
            unsigned int u4 = g[(size_t)s4 * 64 + lane];
            unsigned int u5 = g[(size_t)s5 * 64 + lane];
            unsigned int u6 = g[(size_t)s6 * 64 + lane];
            unsigned int u7 = g[(size_t)s7 * 64 + lane];
            ax += d0 * bf_lo(u0); ay += d0 * bf_hi(u0);
            ax += d1 * bf_lo(u1); ay += d1 * bf_hi(u1);
            ax += d2 * bf_lo(u2); ay += d2 * bf_hi(u2);
            ax += d3 * bf_lo(u3); ay += d3 * bf_hi(u3);
            ax += d4 * bf_lo(u4); ay += d4 * bf_hi(u4);
            ax += d5 * bf_lo(u5); ay += d5 * bf_hi(u5);
            ax += d6 * bf_lo(u6); ay += d6 * bf_hi(u6);
            ax += d7 * bf_lo(u7); ay += d7 * bf_hi(u7);
        }
        for (; j + 3 < m; j += 4) {
            int s0 = __shfl(sc, j),     s1 = __shfl(sc, j + 1);
            int s2 = __shfl(sc, j + 2), s3 = __shfl(sc, j + 3);
            float d0 = __shfl(dsv, j),     d1 = __shfl(dsv, j + 1);
            float d2 = __shfl(dsv, j + 2), d3 = __shfl(dsv, j + 3);
            unsigned int u0 = g[(size_t)s0 * 64 + lane];
            unsigned int u1 = g[(size_t)s1 * 64 + lane];
            unsigned int u2 = g[(size_t)s2 * 64 + lane];
            unsigned int u3 = g[(size_t)s3 * 64 + lane];
            ax += d0 * bf_lo(u0); ay += d0 * bf_hi(u0);
            ax += d1 * bf_lo(u1); ay += d1 * bf_hi(u1);
            ax += d2 * bf_lo(u2); ay += d2 * bf_hi(u2);
            ax += d3 * bf_lo(u3); ay += d3 * bf_hi(u3);
        }
        for (; j < m; ++j) {
            int s0 = __shfl(sc, j);
            float d0 = __shfl(dsv, j);
            unsigned int u0 = g[(size_t)s0 * 64 + lane];
            ax += d0 * bf_lo(u0); ay += d0 * bf_hi(u0);
        }
    }
    oB[(size_t)i * 64 + lane] = pack_bf2(di * ax, di * ay);
}

// ---------------- MFMA matmul (layers 2,3): g_out = bf16(relu(A @ W + b)) -----------
// Wave: 32 nodes x 128 feats; block: 4 waves = 128 nodes. W staged transposed in LDS.

__global__ __launch_bounds__(256) void k_mmx(const unsigned int* __restrict__ gIn,
                                             const float* __restrict__ W,
                                             const float* __restrict__ bias,
                                             unsigned int* __restrict__ outg) {
    __shared__ unsigned short sbuf[128 * 136];   // 34816 B: WT (stride 136), reused as Cs (stride 132)
    int t = threadIdx.x;
    // stage W transposed as bf16: WT[n*136 + k] = bf16(W[k][n])
    for (int i = t; i < 128 * 128; i += 256) {
        int k = i >> 7, n = i & 127;
        sbuf[n * 136 + k] = (unsigned short)f2bf_rne(W[i]);
    }

    int lane = t & 63, wave = t >> 6;
    int m = lane & 15, quad = lane >> 4;
    int nodeBase = blockIdx.x * 128 + wave * 32;
    const short* gs = (const short*)gIn;

    float bi[8];
    #pragma unroll
    for (int nt = 0; nt < 8; ++nt) bi[nt] = bias[nt * 16 + m];

    f32x4 acc[2][8];
    #pragma unroll
    for (int gi = 0; gi < 2; ++gi)
        #pragma unroll
        for (int nt = 0; nt < 8; ++nt)
            acc[gi][nt] = (f32x4){0.f, 0.f, 0.f, 0.f};

    __syncthreads();

    #pragma unroll
    for (int kc = 0; kc < 4; ++kc) {
        bf16x8 ah[2];
        #pragma unroll
        for (int gi = 0; gi < 2; ++gi) {
            int node = nodeBase + gi * 16 + m;
            bf16x8 h = {0, 0, 0, 0, 0, 0, 0, 0};
            if (node < N_NODES)
                h = *(const bf16x8*)(gs + (size_t)node * 128 + kc * 32 + quad * 8);
            ah[gi] = h;
        }
        #pragma unroll
        for (int nt = 0; nt < 8; ++nt) {
            bf16x8 b = *(const bf16x8*)(sbuf + (nt * 16 + m) * 136 + kc * 32 + quad * 8);
            #pragma unroll
            for (int gi = 0; gi < 2; ++gi)
                acc[gi][nt] = __builtin_amdgcn_mfma_f32_16x16x32_bf16(ah[gi], b, acc[gi][nt], 0, 0, 0);
        }
    }

    __syncthreads();   // all waves done reading WT
    // epilogue: bias+relu+bf16, scatter to Cs[node_local][feat], stride 132
    // C/D layout: col=lane&15 (feat m), row=quad*4+reg (node within 16-group)
    #pragma unroll
    for (int gi = 0; gi < 2; ++gi)
        #pragma unroll
        for (int nt = 0; nt < 8; ++nt)
            #pragma unroll
            for (int r = 0; r < 4; ++r) {
                int nl = wave * 32 + gi * 16 + quad * 4 + r;
                float vv = acc[gi][nt][r] + bi[nt];
                sbuf[nl * 132 + nt * 16 + m] = (unsigned short)f2bf_rne(fmaxf(vv, 0.f));
            }
    __syncthreads();
    // cooperative coalesced store: 4 bf16 (uint2) per iteration
    for (int i = t; i < 128 * 32; i += 256) {
        int nl = i >> 5, p = i & 31;
        int node = blockIdx.x * 128 + nl;
        if (node < N_NODES) {
            uint2 val = *(const uint2*)(sbuf + nl * 132 + p * 4);
            *(uint2*)&outg[(size_t)node * 64 + p * 2] = val;
        }
    }
}

// ------------- head weight folding (block 64) + pooled zero-init (blocks 0-63) -------

__global__ void k_wc(const float* __restrict__ W4, const float* __restrict__ b4,
                     const float* __restrict__ Wlin, const float* __restrict__ blin,
                     float* __restrict__ Wc, float* __restrict__ bc,
                     float* __restrict__ pooled) {
    int t = threadIdx.x;
    if (blockIdx.x < 64) {
        // zero pooled: 64 blocks x 256 threads x 4 floats = 65536 = NG*HID
        float4 z = {0.f, 0.f, 0.f, 0.f};
        *(float4*)&pooled[(blockIdx.x * 256 + t) * 4] = z;
        return;
    }
    int k = t >> 1, o = t & 1;
    float acc = 0.f;
    for (int j = 0; j < HID; ++j) acc += W4[k * HID + j] * Wlin[j * 2 + o];
    Wc[k * 2 + o] = acc;
    if (k == 0) {
        float b = blin[o];
        for (int j = 0; j < HID; ++j) b += b4[j] * Wlin[j * 2 + o];
        bc[o] = b;
    }
}

// ---------------- pool stage 1: per-chunk partial sums (bf16 in, fp32 atomics) -------

__global__ __launch_bounds__(256) void k_poolsum(const unsigned int* __restrict__ aggB,
                                                 const int* __restrict__ batch,
                                                 float* __restrict__ pooled) {
    int wid = (blockIdx.x * blockDim.x + threadIdx.x) >> 6;   // wave id: 16 nodes each
    int lane = threadIdx.x & 63;
    int n0 = wid * 16;
    if (n0 >= N_NODES) return;
    int n1 = n0 + 16; if (n1 > N_NODES) n1 = N_NODES;
    int curg = batch[n0];
    float ax = 0.f, ay = 0.f;
    for (int n = n0; n < n1; ++n) {
        int g = batch[n];
        if (g != curg) {
            atomicAdd(&pooled[curg * HID + 2 * lane], ax);
            atomicAdd(&pooled[curg * HID + 2 * lane + 1], ay);
            ax = 0.f; ay = 0.f; curg = g;
        }
        unsigned int u = aggB[(size_t)n * 64 + lane];
        ax += bf_lo(u); ay += bf_hi(u);
    }
    atomicAdd(&pooled[curg * HID + 2 * lane], ax);
    atomicAdd(&pooled[curg * HID + 2 * lane + 1], ay);
}

// ---------------- head: mean + fused W4*Wlin linear ----------------

__global__ void k_head(const float* __restrict__ pooled, const int* __restrict__ batch,
                       const float* __restrict__ Wc, const float* __restrict__ bc,
                       const float* __restrict__ blin, float* __restrict__ out) {
    int wid = (blockIdx.x * blockDim.x + threadIdx.x) >> 6;
    int lane = threadIdx.x & 63;
    if (wid >= NG) return;
    int g = wid;
    int lo = 0, hi = N_NODES;
    while (lo < hi) { int mid = (lo + hi) >> 1; if (batch[mid] < g) lo = mid + 1; else hi = mid; }
    int start = lo;
    hi = N_NODES;
    while (lo < hi) { int mid = (lo + hi) >> 1; if (batch[mid] < g + 1) lo = mid + 1; else hi = mid; }
    int cnt = lo - start;
    float invc = (cnt > 0) ? 1.0f / (float)cnt : 0.f;
    float px = pooled[g * HID + 2 * lane] * invc;
    float py = pooled[g * HID + 2 * lane + 1] * invc;

    #pragma unroll
    for (int o = 0; o < 2; ++o) {
        float v = px * Wc[(2 * lane) * 2 + o] + py * Wc[(2 * lane + 1) * 2 + o];
        #pragma unroll
        for (int s = 32; s > 0; s >>= 1) v += __shfl_down(v, s);
        if (lane == 0) out[g * 2 + o] = (cnt > 0) ? (v + bc[o]) : blin[o];
    }
}

// ---------------- launcher ----------------

extern "C" void kernel_launch(void* const* d_in, const int* in_sizes, int n_in,
                              void* d_out, int out_size, void* d_ws, size_t ws_size,
                              hipStream_t stream) {
    const float* x    = (const float*)d_in[0];
    const int*   eidx = (const int*)d_in[1];
    const int*   batch= (const int*)d_in[2];
    const float* W1   = (const float*)d_in[3];
    const float* b1   = (const float*)d_in[4];
    const float* W2   = (const float*)d_in[5];
    const float* b2   = (const float*)d_in[6];
    const float* W3   = (const float*)d_in[7];
    const float* b3   = (const float*)d_in[8];
    const float* W4   = (const float*)d_in[9];
    const float* b4   = (const float*)d_in[10];
    const float* Wlin = (const float*)d_in[11];
    const float* blin = (const float*)d_in[12];
    float* out = (float*)d_out;

    // workspace carve-up (256B aligned)
    char* ws = (char*)d_ws;
    size_t off = 0;
    auto carve = [&](size_t bytes) { char* p = ws + off; off = (off + bytes + 255) & ~(size_t)255; return p; };
    int*   rowptr    = (int*)carve((size_t)(N_NODES + 1) * 4);
    float* dinv      = (float*)carve((size_t)N_NODES * 4);
    int*   col       = (int*)carve((size_t)E_EDGES * 4);
    unsigned int* ebuf = (unsigned int*)carve((size_t)E_EDGES * 4);
    int*   table     = (int*)carve((size_t)TLEN * 4);
    int*   partial   = (int*)carve((size_t)NCH * 4);
    int*   bucketBase= (int*)carve((size_t)(NBUCK + 1) * 4);
    float* aggx      = (float*)carve((size_t)N_NODES * FIN * 4);
    unsigned int* gA = (unsigned int*)carve((size_t)N_NODES * 64 * 4);   // 25.6 MB bf16 buffer
    unsigned int* gB = (unsigned int*)carve((size_t)N_NODES * 64 * 4);   // 25.6 MB bf16 buffer
    float* pooled    = (float*)carve((size_t)NG * HID * 4);
    float* Wc        = (float*)carve((size_t)HID * 2 * 4);
    float* bc        = (float*)carve(2 * 4);
    (void)ws_size; (void)n_in; (void)in_sizes; (void)out_size;

    const int BLK = 256;
    int gridN = (N_NODES + BLK - 1) / BLK;
    int gridAgg = (N_NODES * 64 + BLK - 1) / BLK;
    int gridMM1 = (N_NODES * 64 + BLK - 1) / BLK;
    int gridPS = ((N_NODES + 15) / 16 * 64 + BLK - 1) / BLK;
    int gridHead = (NG * 64 + BLK - 1) / BLK;

    // CSR build (radix partition: hist -> scan -> scatter -> bucket finalize)
    k_hist2<<<NBLK_SC, BLK, 0, stream>>>(eidx, table);
    k_blocksum<<<NCH, BLK, 0, stream>>>(table, partial);
    k_scan_blk<<<1, 64, 0, stream>>>(partial, bucketBase, rowptr);
    k_scan_final<<<NCH, 1024, 0, stream>>>(table, partial, bucketBase);
    k_scatter2<<<NBLK_SC, BLK, 0, stream>>>(eidx, table, ebuf);
    k_bucket<<<NBUCK, BLK, 0, stream>>>(ebuf, bucketBase, rowptr, dinv, col);

    // head weight folding + pooled zero-init (independent of graph pipeline)
    k_wc<<<65, 256, 0, stream>>>(W4, b4, Wlin, blin, Wc, bc, pooled);

    // layer 1: g1 = bf16(relu((A' x) W1 + b1))
    k_agg7<<<gridN, BLK, 0, stream>>>(x, rowptr, col, dinv, aggx);
    k_mm1<<<gridMM1, BLK, 0, stream>>>(aggx, W1, b1, gA);

    // layer 2: a2 = bf16(A' g1) -> MFMA mm -> g2
    k_agg128<<<gridAgg, BLK, 0, stream>>>(gA, gB, rowptr, col, dinv);
    k_mmx<<<MMX_GRID, BLK, 0, stream>>>(gB, W2, b2, gA);
    // layer 3: a3 = bf16(A' g2) -> MFMA mm -> g3
    k_agg128<<<gridAgg, BLK, 0, stream>>>(gA, gB, rowptr, col, dinv);
    k_mmx<<<MMX_GRID, BLK, 0, stream>>>(gB, W3, b3, gA);
    // layer 4: aggregation only (W4 folded into head), bf16 out
    k_agg128<<<gridAgg, BLK, 0, stream>>>(gA, gB, rowptr, col, dinv);

    // pool + head
    k_poolsum<<<gridPS, BLK, 0, stream>>>(gB, batch, pooled);
    k_head<<<gridHead, BLK, 0, stream>>>(pooled, batch, Wc, bc, blin, out);
}

// Round 11
// 419.110 us; speedup vs baseline: 1.4667x; 1.0974x over previous
//
#include <hip/hip_runtime.h>
#include <hip/hip_bf16.h>

#define N_NODES 100000
#define E_EDGES 1600000
#define NG 512
#define FIN 7
#define HID 128
#define NBUCK 782          // ceil(N_NODES/128), bucket = 128 consecutive dst nodes
#define NBLK_SC 256        // partition blocks (each owns a contiguous edge chunk)
#define CHUNK 6250         // E_EDGES / NBLK_SC (exact)
#define TLEN (NBUCK * NBLK_SC)   // 200192 table entries
#define NCH 196            // ceil(TLEN/1024) scan chunks
#define MMX_GRID 782       // ceil(N_NODES/128)

typedef __attribute__((ext_vector_type(8))) short bf16x8;
typedef __attribute__((ext_vector_type(4))) float f32x4;

// bf16 helpers: decode packed pair, encode with RNE
__device__ __forceinline__ float bf_lo(unsigned int u) { return __uint_as_float(u << 16); }
__device__ __forceinline__ float bf_hi(unsigned int u) { return __uint_as_float(u & 0xffff0000u); }
__device__ __forceinline__ unsigned int f2bf_rne(float f) {
    unsigned int x = __float_as_uint(f);
    return (x + 0x7fffu + ((x >> 16) & 1u)) >> 16;   // finite inputs only
}
__device__ __forceinline__ unsigned int pack_bf2(float lo, float hi) {
    return f2bf_rne(lo) | (f2bf_rne(hi) << 16);
}

// ------------- CSR hist (blocks 0..255) + pooled zero (256..319) + Wc fold (320) -----

__global__ __launch_bounds__(256) void k_hist2(const int* __restrict__ eidx,
                                               int* __restrict__ table,
                                               const float* __restrict__ W4,
                                               const float* __restrict__ b4,
                                               const float* __restrict__ Wlin,
                                               const float* __restrict__ blin,
                                               float* __restrict__ Wc,
                                               float* __restrict__ bc,
                                               float* __restrict__ pooled) {
    __shared__ int h[NBUCK];
    int blk = blockIdx.x, t = threadIdx.x;
    if (blk >= NBLK_SC) {
        int r = blk - NBLK_SC;
        if (r < 64) {
            float4 z = {0.f, 0.f, 0.f, 0.f};
            *(float4*)&pooled[(r * 256 + t) * 4] = z;   // 64*256*16B = NG*HID*4
        } else {
            int k = t >> 1, o = t & 1;
            float acc = 0.f;
            for (int j = 0; j < HID; ++j) acc += W4[k * HID + j] * Wlin[j * 2 + o];
            Wc[k * 2 + o] = acc;
            if (k == 0) {
                float b = blin[o];
                for (int j = 0; j < HID; ++j) b += b4[j] * Wlin[j * 2 + o];
                bc[o] = b;
            }
        }
        return;
    }
    for (int i = t; i < NBUCK; i += 256) h[i] = 0;
    __syncthreads();
    int e0 = blk * CHUNK, e1 = e0 + CHUNK;
    for (int e = e0 + t; e < e1; e += 256)
        atomicAdd(&h[eidx[E_EDGES + e] >> 7], 1);
    __syncthreads();
    for (int i = t; i < NBUCK; i += 256)
        table[i * NBLK_SC + blk] = h[i];
}

__global__ void k_blocksum(const int* __restrict__ table, int* __restrict__ partial) {
    __shared__ int s[256];
    int b = blockIdx.x, t = threadIdx.x;
    int base = b * 1024;
    int sum = 0;
    for (int i = t; i < 1024; i += 256) {
        int idx = base + i;
        sum += (idx < TLEN) ? table[idx] : 0;
    }
    s[t] = sum; __syncthreads();
    for (int st = 128; st > 0; st >>= 1) {
        if (t < st) s[t] += s[t + st];
        __syncthreads();
    }
    if (t == 0) partial[b] = s[0];
}

__global__ void k_scan_blk(int* __restrict__ partial, int* __restrict__ bucketBase,
                           int* __restrict__ rowptr) {
    if (threadIdx.x == 0 && blockIdx.x == 0) {
        int run = 0;
        for (int i = 0; i < NCH; ++i) { int v = partial[i]; partial[i] = run; run += v; }
        bucketBase[NBUCK] = E_EDGES;
        rowptr[N_NODES] = E_EDGES;
    }
}

__global__ void k_scan_final(int* __restrict__ table, const int* __restrict__ partial,
                             int* __restrict__ bucketBase) {
    __shared__ int s[1024];
    int b = blockIdx.x, t = threadIdx.x;
    int idx = b * 1024 + t;
    int v = (idx < TLEN) ? table[idx] : 0;
    s[t] = v; __syncthreads();
    for (int st = 1; st < 1024; st <<= 1) {
        int add = (t >= st) ? s[t - st] : 0;
        __syncthreads();
        s[t] += add;
        __syncthreads();
    }
    if (idx < TLEN) {
        int ex = partial[b] + s[t] - v;   // exclusive
        table[idx] = ex;
        if ((idx & (NBLK_SC - 1)) == 0) bucketBase[idx / NBLK_SC] = ex;
    }
}

__global__ __launch_bounds__(256) void k_scatter2(const int* __restrict__ eidx,
                                                  const int* __restrict__ table,
                                                  unsigned int* __restrict__ ebuf) {
    __shared__ int loff[NBUCK];
    int blk = blockIdx.x, t = threadIdx.x;
    for (int i = t; i < NBUCK; i += 256) loff[i] = table[i * NBLK_SC + blk];
    __syncthreads();
    int e0 = blk * CHUNK, e1 = e0 + CHUNK;
    for (int e = e0 + t; e < e1; e += 256) {
        int s = eidx[e];
        int d = eidx[E_EDGES + e];
        int p = atomicAdd(&loff[d >> 7], 1);
        ebuf[p] = ((unsigned int)(d & 127) << 17) | (unsigned int)s;
    }
}

__global__ __launch_bounds__(256) void k_bucket(const unsigned int* __restrict__ ebuf,
                                                const int* __restrict__ bucketBase,
                                                int* __restrict__ rowptr,
                                                float* __restrict__ dinv,
                                                int* __restrict__ col) {
    __shared__ int scnt[128], soff[128], scur[128];
    int b = blockIdx.x, t = threadIdx.x;
    int bbase = bucketBase[b], bend = bucketBase[b + 1];
    if (t < 128) { scnt[t] = 0; scur[t] = 0; }
    __syncthreads();
    for (int e = bbase + t; e < bend; e += 256) {
        unsigned int rec = ebuf[e];
        atomicAdd(&scnt[rec >> 17], 1);
    }
    __syncthreads();
    if (t < 128) soff[t] = scnt[t];
    __syncthreads();
    for (int st = 1; st < 128; st <<= 1) {
        int a = (t < 128 && t >= st) ? soff[t - st] : 0;
        __syncthreads();
        if (t < 128) soff[t] += a;
        __syncthreads();
    }
    if (t < 128) {
        int ex = soff[t] - scnt[t];
        int node = b * 128 + t;
        if (node < N_NODES) {
            rowptr[node] = bbase + ex;
            dinv[node] = rsqrtf((float)(scnt[t] + 1));   // +1 self-loop
        }
        soff[t] = ex;
    }
    __syncthreads();
    for (int e = bbase + t; e < bend; e += 256) {
        unsigned int rec = ebuf[e];
        int dl = rec >> 17;
        int s = rec & 0x1FFFF;
        int p = bbase + soff[dl] + atomicAdd(&scur[dl], 1);
        col[p] = s;
    }
}

// ---------------- fused layer 1: g1 = bf16(relu((A' x) W1 + b1)) ----------------
// Phase A: cooperative gather, 8 lanes/node (f<7: x feature f; f==7: dinv).
// Phase B: 32-node tile matmul from LDS. Block = 256 thr = 4 waves = 32 nodes.

__global__ __launch_bounds__(256) void k_l1(const float* __restrict__ x,
                                            const float* __restrict__ W1,
                                            const float* __restrict__ b1,
                                            const int* __restrict__ rowptr,
                                            const int* __restrict__ col,
                                            const float* __restrict__ dinv,
                                            unsigned int* __restrict__ g1) {
    __shared__ float axs[32][8];       // 32 nodes x 7 feats (+pad)
    __shared__ float w1s[FIN * HID];   // 3.5 KB
    __shared__ float b1s[HID];
    int t = threadIdx.x;
    for (int i = t; i < FIN * HID; i += 256) w1s[i] = W1[i];
    if (t < HID) b1s[t] = b1[t];

    int lane = t & 63, wave = t >> 6;
    int sub = lane >> 3, f = lane & 7;          // node-subgroup, lane role
    int node = blockIdx.x * 32 + wave * 8 + sub;
    bool valid = node < N_NODES;
    float di = valid ? dinv[node] : 0.f;
    float a = (valid && f < 7) ? di * x[node * FIN + f] : 0.f;
    int e0 = valid ? rowptr[node] : 0;
    int e1 = valid ? rowptr[node + 1] : 0;
    for (int base = e0; base < e1; base += 8) {
        int mm = e1 - base; if (mm > 8) mm = 8;
        int sc = (f < mm) ? col[base + f] : 0;
        for (int j = 0; j < mm; ++j) {
            int s = __shfl(sc, sub * 8 + j);
            float v = (f < 7) ? x[s * FIN + f] : dinv[s];
            float ds = __shfl(v, sub * 8 + 7);
            if (f < 7) a += ds * v;
        }
    }
    axs[wave * 8 + sub][f] = (f < 7) ? di * a : 0.f;
    __syncthreads();

    // phase B: thread t -> node nl=t>>3, feat-block fb=t&7 (16 feats)
    int nl = t >> 3, fb = t & 7;
    int gnode = blockIdx.x * 32 + nl;
    if (gnode < N_NODES) {
        float av[FIN];
        #pragma unroll
        for (int k = 0; k < FIN; ++k) av[k] = axs[nl][k];
        unsigned int outp[8];
        #pragma unroll
        for (int p = 0; p < 8; ++p) {
            int fo = fb * 16 + p * 2;
            float acc0 = b1s[fo], acc1 = b1s[fo + 1];
            #pragma unroll
            for (int k = 0; k < FIN; ++k) {
                acc0 += av[k] * w1s[k * HID + fo];
                acc1 += av[k] * w1s[k * HID + fo + 1];
            }
            outp[p] = pack_bf2(fmaxf(acc0, 0.f), fmaxf(acc1, 0.f));
        }
        *(uint4*)&g1[(size_t)gnode * 64 + fb * 8] = *(uint4*)&outp[0];
        *(uint4*)&g1[(size_t)gnode * 64 + fb * 8 + 4] = *(uint4*)&outp[4];
    }
}

// ---------------- 128-wide aggregation (wave/node, bf16 gather, shfl-batched) --------

__global__ void k_agg128(const unsigned int* __restrict__ g,   // packed bf16 pairs [N][64]
                         unsigned int* __restrict__ oB,
                         const int* __restrict__ rowptr, const int* __restrict__ col,
                         const float* __restrict__ dinv) {
    int wid = (blockIdx.x * blockDim.x + threadIdx.x) >> 6;
    int lane = threadIdx.x & 63;
    if (wid >= N_NODES) return;
    int i = wid;
    float di = dinv[i];
    unsigned int v = g[(size_t)i * 64 + lane];
    float ax = di * bf_lo(v), ay = di * bf_hi(v);
    int e0 = rowptr[i], e1 = rowptr[i + 1];
    for (int base = e0; base < e1; base += 64) {
        int m = e1 - base; if (m > 64) m = 64;
        int sc = 0; float dsv = 0.f;
        if (lane < m) { sc = col[base + lane]; dsv = dinv[sc]; }
        int j = 0;
        for (; j + 7 < m; j += 8) {
            int s0 = __shfl(sc, j),     s1 = __shfl(sc, j + 1);
            int s2 = __shfl(sc, j + 2), s3 = __shfl(sc, j + 3);
            int s4 = __shfl(sc, j + 4), s5 = __shfl(sc, j + 5);
            int s6 = __shfl(sc, j + 6), s7 = __shfl(sc, j + 7);
            float d0 = __shfl(dsv, j),     d1 = __shfl(dsv, j + 1);
            float d2 = __shfl(dsv, j + 2), d3 = __shfl(dsv, j + 3);
            float d4 = __shfl(dsv, j + 4), d5 = __shfl(dsv, j + 5);
            float d6 = __shfl(dsv, j + 6), d7 = __shfl(dsv, j + 7);
            unsigned int u0 = g[(size_t)s0 * 64 + lane];
            unsigned int u1 = g[(size_t)s1 * 64 + lane];
            unsigned int u2 = g[(size_t)s2 * 64 + lane];
            unsigned int u3 = g[(size_t)s3 * 64 + lane];
            unsigned int u4 = g[(size_t)s4 * 64 + lane];
            unsigned int u5 = g[(size_t)s5 * 64 + lane];
            unsigned int u6 = g[(size_t)s6 * 64 + lane];
            unsigned int u7 = g[(size_t)s7 * 64 + lane];
            ax += d0 * bf_lo(u0); ay += d0 * bf_hi(u0);
            ax += d1 * bf_lo(u1); ay += d1 * bf_hi(u1);
            ax += d2 * bf_lo(u2); ay += d2 * bf_hi(u2);
            ax += d3 * bf_lo(u3); ay += d3 * bf_hi(u3);
            ax += d4 * bf_lo(u4); ay += d4 * bf_hi(u4);
            ax += d5 * bf_lo(u5); ay += d5 * bf_hi(u5);
            ax += d6 * bf_lo(u6); ay += d6 * bf_hi(u6);
            ax += d7 * bf_lo(u7); ay += d7 * bf_hi(u7);
        }
        for (; j + 3 < m; j += 4) {
            int s0 = __shfl(sc, j),     s1 = __shfl(sc, j + 1);
            int s2 = __shfl(sc, j + 2), s3 = __shfl(sc, j + 3);
            float d0 = __shfl(dsv, j),     d1 = __shfl(dsv, j + 1);
            float d2 = __shfl(dsv, j + 2), d3 = __shfl(dsv, j + 3);
            unsigned int u0 = g[(size_t)s0 * 64 + lane];
            unsigned int u1 = g[(size_t)s1 * 64 + lane];
            unsigned int u2 = g[(size_t)s2 * 64 + lane];
            unsigned int u3 = g[(size_t)s3 * 64 + lane];
            ax += d0 * bf_lo(u0); ay += d0 * bf_hi(u0);
            ax += d1 * bf_lo(u1); ay += d1 * bf_hi(u1);
            ax += d2 * bf_lo(u2); ay += d2 * bf_hi(u2);
            ax += d3 * bf_lo(u3); ay += d3 * bf_hi(u3);
        }
        for (; j < m; ++j) {
            int s0 = __shfl(sc, j);
            float d0 = __shfl(dsv, j);
            unsigned int u0 = g[(size_t)s0 * 64 + lane];
            ax += d0 * bf_lo(u0); ay += d0 * bf_hi(u0);
        }
    }
    oB[(size_t)i * 64 + lane] = pack_bf2(di * ax, di * ay);
}

// ---------------- MFMA matmul (layers 2,3): g_out = bf16(relu(A @ W + b)) -----------

__global__ __launch_bounds__(256) void k_mmx(const unsigned int* __restrict__ gIn,
                                             const float* __restrict__ W,
                                             const float* __restrict__ bias,
                                             unsigned int* __restrict__ outg) {
    __shared__ unsigned short sbuf[128 * 136];   // WT (stride 136), reused as Cs (stride 132)
    int t = threadIdx.x;
    for (int i = t; i < 128 * 128; i += 256) {
        int k = i >> 7, n = i & 127;
        sbuf[n * 136 + k] = (unsigned short)f2bf_rne(W[i]);
    }

    int lane = t & 63, wave = t >> 6;
    int m = lane & 15, quad = lane >> 4;
    int nodeBase = blockIdx.x * 128 + wave * 32;
    const short* gs = (const short*)gIn;

    float bi[8];
    #pragma unroll
    for (int nt = 0; nt < 8; ++nt) bi[nt] = bias[nt * 16 + m];

    f32x4 acc[2][8];
    #pragma unroll
    for (int gi = 0; gi < 2; ++gi)
        #pragma unroll
        for (int nt = 0; nt < 8; ++nt)
            acc[gi][nt] = (f32x4){0.f, 0.f, 0.f, 0.f};

    __syncthreads();

    #pragma unroll
    for (int kc = 0; kc < 4; ++kc) {
        bf16x8 ah[2];
        #pragma unroll
        for (int gi = 0; gi < 2; ++gi) {
            int node = nodeBase + gi * 16 + m;
            bf16x8 h = {0, 0, 0, 0, 0, 0, 0, 0};
            if (node < N_NODES)
                h = *(const bf16x8*)(gs + (size_t)node * 128 + kc * 32 + quad * 8);
            ah[gi] = h;
        }
        #pragma unroll
        for (int nt = 0; nt < 8; ++nt) {
            bf16x8 b = *(const bf16x8*)(sbuf + (nt * 16 + m) * 136 + kc * 32 + quad * 8);
            #pragma unroll
            for (int gi = 0; gi < 2; ++gi)
                acc[gi][nt] = __builtin_amdgcn_mfma_f32_16x16x32_bf16(ah[gi], b, acc[gi][nt], 0, 0, 0);
        }
    }

    __syncthreads();
    #pragma unroll
    for (int gi = 0; gi < 2; ++gi)
        #pragma unroll
        for (int nt = 0; nt < 8; ++nt)
            #pragma unroll
            for (int r = 0; r < 4; ++r) {
                int nl = wave * 32 + gi * 16 + quad * 4 + r;
                float vv = acc[gi][nt][r] + bi[nt];
                sbuf[nl * 132 + nt * 16 + m] = (unsigned short)f2bf_rne(fmaxf(vv, 0.f));
            }
    __syncthreads();
    for (int i = t; i < 128 * 32; i += 256) {
        int nl = i >> 5, p = i & 31;
        int node = blockIdx.x * 128 + nl;
        if (node < N_NODES) {
            uint2 val = *(const uint2*)(sbuf + nl * 132 + p * 4);
            *(uint2*)&outg[(size_t)node * 64 + p * 2] = val;
        }
    }
}

// ---------------- pool stage 1: per-chunk partial sums (bf16 in, fp32 atomics) -------

__global__ __launch_bounds__(256) void k_poolsum(const unsigned int* __restrict__ aggB,
                                                 const int* __restrict__ batch,
                                                 float* __restrict__ pooled) {
    int wid = (blockIdx.x * blockDim.x + threadIdx.x) >> 6;   // wave id: 16 nodes each
    int lane = threadIdx.x & 63;
    int n0 = wid * 16;
    if (n0 >= N_NODES) return;
    int n1 = n0 + 16; if (n1 > N_NODES) n1 = N_NODES;
    int curg = batch[n0];
    float ax = 0.f, ay = 0.f;
    for (int n = n0; n < n1; ++n) {
        int g = batch[n];
        if (g != curg) {
            atomicAdd(&pooled[curg * HID + 2 * lane], ax);
            atomicAdd(&pooled[curg * HID + 2 * lane + 1], ay);
            ax = 0.f; ay = 0.f; curg = g;
        }
        unsigned int u = aggB[(size_t)n * 64 + lane];
        ax += bf_lo(u); ay += bf_hi(u);
    }
    atomicAdd(&pooled[curg * HID + 2 * lane], ax);
    atomicAdd(&pooled[curg * HID + 2 * lane + 1], ay);
}

// ---------------- head: mean + fused W4*Wlin linear ----------------

__global__ void k_head(const float* __restrict__ pooled, const int* __restrict__ batch,
                       const float* __restrict__ Wc, const float* __restrict__ bc,
                       const float* __restrict__ blin, float* __restrict__ out) {
    int wid = (blockIdx.x * blockDim.x + threadIdx.x) >> 6;
    int lane = threadIdx.x & 63;
    if (wid >= NG) return;
    int g = wid;
    int lo = 0, hi = N_NODES;
    while (lo < hi) { int mid = (lo + hi) >> 1; if (batch[mid] < g) lo = mid + 1; else hi = mid; }
    int start = lo;
    hi = N_NODES;
    while (lo < hi) { int mid = (lo + hi) >> 1; if (batch[mid] < g + 1) lo = mid + 1; else hi = mid; }
    int cnt = lo - start;
    float invc = (cnt > 0) ? 1.0f / (float)cnt : 0.f;
    float px = pooled[g * HID + 2 * lane] * invc;
    float py = pooled[g * HID + 2 * lane + 1] * invc;

    #pragma unroll
    for (int o = 0; o < 2; ++o) {
        float v = px * Wc[(2 * lane) * 2 + o] + py * Wc[(2 * lane + 1) * 2 + o];
        #pragma unroll
        for (int s = 32; s > 0; s >>= 1) v += __shfl_down(v, s);
        if (lane == 0) out[g * 2 + o] = (cnt > 0) ? (v + bc[o]) : blin[o];
    }
}

// ---------------- launcher ----------------

extern "C" void kernel_launch(void* const* d_in, const int* in_sizes, int n_in,
                              void* d_out, int out_size, void* d_ws, size_t ws_size,
                              hipStream_t stream) {
    const float* x    = (const float*)d_in[0];
    const int*   eidx = (const int*)d_in[1];
    const int*   batch= (const int*)d_in[2];
    const float* W1   = (const float*)d_in[3];
    const float* b1   = (const float*)d_in[4];
    const float* W2   = (const float*)d_in[5];
    const float* b2   = (const float*)d_in[6];
    const float* W3   = (const float*)d_in[7];
    const float* b3   = (const float*)d_in[8];
    const float* W4   = (const float*)d_in[9];
    const float* b4   = (const float*)d_in[10];
    const float* Wlin = (const float*)d_in[11];
    const float* blin = (const float*)d_in[12];
    float* out = (float*)d_out;

    // workspace carve-up (256B aligned)
    char* ws = (char*)d_ws;
    size_t off = 0;
    auto carve = [&](size_t bytes) { char* p = ws + off; off = (off + bytes + 255) & ~(size_t)255; return p; };
    int*   rowptr    = (int*)carve((size_t)(N_NODES + 1) * 4);
    float* dinv      = (float*)carve((size_t)N_NODES * 4);
    int*   col       = (int*)carve((size_t)E_EDGES * 4);
    unsigned int* ebuf = (unsigned int*)carve((size_t)E_EDGES * 4);
    int*   table     = (int*)carve((size_t)TLEN * 4);
    int*   partial   = (int*)carve((size_t)NCH * 4);
    int*   bucketBase= (int*)carve((size_t)(NBUCK + 1) * 4);
    unsigned int* gA = (unsigned int*)carve((size_t)N_NODES * 64 * 4);   // 25.6 MB bf16 buffer
    unsigned int* gB = (unsigned int*)carve((size_t)N_NODES * 64 * 4);   // 25.6 MB bf16 buffer
    float* pooled    = (float*)carve((size_t)NG * HID * 4);
    float* Wc        = (float*)carve((size_t)HID * 2 * 4);
    float* bc        = (float*)carve(2 * 4);
    (void)ws_size; (void)n_in; (void)in_sizes; (void)out_size;

    const int BLK = 256;
    int gridAgg = (N_NODES * 64 + BLK - 1) / BLK;
    int gridL1 = (N_NODES + 31) / 32;               // 3125
    int gridPS = ((N_NODES + 15) / 16 * 64 + BLK - 1) / BLK;
    int gridHead = (NG * 64 + BLK - 1) / BLK;

    // CSR build (radix partition) + head-weight fold + pooled zero (fused into hist)
    k_hist2<<<NBLK_SC + 65, BLK, 0, stream>>>(eidx, table, W4, b4, Wlin, blin, Wc, bc, pooled);
    k_blocksum<<<NCH, BLK, 0, stream>>>(table, partial);
    k_scan_blk<<<1, 64, 0, stream>>>(partial, bucketBase, rowptr);
    k_scan_final<<<NCH, 1024, 0, stream>>>(table, partial, bucketBase);
    k_scatter2<<<NBLK_SC, BLK, 0, stream>>>(eidx, table, ebuf);
    k_bucket<<<NBUCK, BLK, 0, stream>>>(ebuf, bucketBase, rowptr, dinv, col);

    // layer 1 (fused agg + matmul)
    k_l1<<<gridL1, BLK, 0, stream>>>(x, W1, b1, rowptr, col, dinv, gA);

    // layer 2: a2 = bf16(A' g1) -> MFMA mm -> g2
    k_agg128<<<gridAgg, BLK, 0, stream>>>(gA, gB, rowptr, col, dinv);
    k_mmx<<<MMX_GRID, BLK, 0, stream>>>(gB, W2, b2, gA);
    // layer 3: a3 = bf16(A' g2) -> MFMA mm -> g3
    k_agg128<<<gridAgg, BLK, 0, stream>>>(gA, gB, rowptr, col, dinv);
    k_mmx<<<MMX_GRID, BLK, 0, stream>>>(gB, W3, b3, gA);
    // layer 4: aggregation only (W4 folded into head), bf16 out
    k_agg128<<<gridAgg, BLK, 0, stream>>>(gA, gB, rowptr, col, dinv);

    // pool + head
    k_poolsum<<<gridPS, BLK, 0, stream>>>(gB, batch, pooled);
    k_head<<<gridHead, BLK, 0, stream>>>(pooled, batch, Wc, bc, blin, out);
}

// Round 12
// 409.491 us; speedup vs baseline: 1.5011x; 1.0235x over previous
//
#include <hip/hip_runtime.h>
#include <hip/hip_bf16.h>

#define N_NODES 100000
#define E_EDGES 1600000
#define NG 512
#define FIN 7
#define HID 128
#define NBUCK 782          // ceil(N_NODES/128), bucket = 128 consecutive dst nodes
#define NBLK_SC 256        // partition blocks (each owns a contiguous edge chunk)
#define CHUNK 6250         // E_EDGES / NBLK_SC (exact)
#define TLEN (NBUCK * NBLK_SC)   // 200192 table entries
#define NCH 196            // ceil(TLEN/1024) scan chunks
#define MMX_GRID 782       // ceil(N_NODES/128)

typedef __attribute__((ext_vector_type(8))) short bf16x8;
typedef __attribute__((ext_vector_type(4))) float f32x4;

// bf16 helpers: decode packed pair, encode with RNE
__device__ __forceinline__ float bf_lo(unsigned int u) { return __uint_as_float(u << 16); }
__device__ __forceinline__ float bf_hi(unsigned int u) { return __uint_as_float(u & 0xffff0000u); }
__device__ __forceinline__ unsigned int f2bf_rne(float f) {
    unsigned int x = __float_as_uint(f);
    return (x + 0x7fffu + ((x >> 16) & 1u)) >> 16;   // finite inputs only
}
__device__ __forceinline__ unsigned int pack_bf2(float lo, float hi) {
    return f2bf_rne(lo) | (f2bf_rne(hi) << 16);
}

// ------ CSR hist (0..255) + pooled zero (256..319) + Wc fold (320) + WT2/WT3 (321..448)

__global__ __launch_bounds__(256) void k_hist2(const int* __restrict__ eidx,
                                               int* __restrict__ table,
                                               const float* __restrict__ W4,
                                               const float* __restrict__ b4,
                                               const float* __restrict__ Wlin,
                                               const float* __restrict__ blin,
                                               float* __restrict__ Wc,
                                               float* __restrict__ bc,
                                               float* __restrict__ pooled,
                                               const float* __restrict__ W2,
                                               const float* __restrict__ W3,
                                               unsigned short* __restrict__ WT2,
                                               unsigned short* __restrict__ WT3) {
    __shared__ int h[NBUCK];
    int blk = blockIdx.x, t = threadIdx.x;
    if (blk >= NBLK_SC) {
        int r = blk - NBLK_SC;
        if (r < 64) {
            float4 z = {0.f, 0.f, 0.f, 0.f};
            *(float4*)&pooled[(r * 256 + t) * 4] = z;   // 64*256*16B = NG*HID*4
        } else if (r == 64) {
            int k = t >> 1, o = t & 1;
            float acc = 0.f;
            for (int j = 0; j < HID; ++j) acc += W4[k * HID + j] * Wlin[j * 2 + o];
            Wc[k * 2 + o] = acc;
            if (k == 0) {
                float b = blin[o];
                for (int j = 0; j < HID; ++j) b += b4[j] * Wlin[j * 2 + o];
                bc[o] = b;
            }
        } else if (r < 129) {   // WT2: transpose+convert, 64 blocks x 256 = 16384 elems
            int idx = (r - 65) * 256 + t;
            int k = idx >> 7, n = idx & 127;
            WT2[n * 128 + k] = (unsigned short)f2bf_rne(W2[idx]);
        } else {                // WT3
            int idx = (r - 129) * 256 + t;
            int k = idx >> 7, n = idx & 127;
            WT3[n * 128 + k] = (unsigned short)f2bf_rne(W3[idx]);
        }
        return;
    }
    for (int i = t; i < NBUCK; i += 256) h[i] = 0;
    __syncthreads();
    int e0 = blk * CHUNK, e1 = e0 + CHUNK;
    for (int e = e0 + t; e < e1; e += 256)
        atomicAdd(&h[eidx[E_EDGES + e] >> 7], 1);
    __syncthreads();
    for (int i = t; i < NBUCK; i += 256)
        table[i * NBLK_SC + blk] = h[i];
}

__global__ void k_blocksum(const int* __restrict__ table, int* __restrict__ partial) {
    __shared__ int s[256];
    int b = blockIdx.x, t = threadIdx.x;
    int base = b * 1024;
    int sum = 0;
    for (int i = t; i < 1024; i += 256) {
        int idx = base + i;
        sum += (idx < TLEN) ? table[idx] : 0;
    }
    s[t] = sum; __syncthreads();
    for (int st = 128; st > 0; st >>= 1) {
        if (t < st) s[t] += s[t + st];
        __syncthreads();
    }
    if (t == 0) partial[b] = s[0];
}

// parallel exclusive scan of the 196 chunk sums (one 256-thread block)
__global__ void k_scan_blk(int* __restrict__ partial, int* __restrict__ bucketBase,
                           int* __restrict__ rowptr) {
    __shared__ int s[256];
    int t = threadIdx.x;
    int v = (t < NCH) ? partial[t] : 0;
    s[t] = v; __syncthreads();
    for (int st = 1; st < 256; st <<= 1) {
        int a = (t >= st) ? s[t - st] : 0;
        __syncthreads();
        s[t] += a;
        __syncthreads();
    }
    if (t < NCH) partial[t] = s[t] - v;   // exclusive
    if (t == 0) { bucketBase[NBUCK] = E_EDGES; rowptr[N_NODES] = E_EDGES; }
}

__global__ void k_scan_final(int* __restrict__ table, const int* __restrict__ partial,
                             int* __restrict__ bucketBase) {
    __shared__ int s[1024];
    int b = blockIdx.x, t = threadIdx.x;
    int idx = b * 1024 + t;
    int v = (idx < TLEN) ? table[idx] : 0;
    s[t] = v; __syncthreads();
    for (int st = 1; st < 1024; st <<= 1) {
        int add = (t >= st) ? s[t - st] : 0;
        __syncthreads();
        s[t] += add;
        __syncthreads();
    }
    if (idx < TLEN) {
        int ex = partial[b] + s[t] - v;   // exclusive
        table[idx] = ex;
        if ((idx & (NBLK_SC - 1)) == 0) bucketBase[idx / NBLK_SC] = ex;
    }
}

__global__ __launch_bounds__(256) void k_scatter2(const int* __restrict__ eidx,
                                                  const int* __restrict__ table,
                                                  unsigned int* __restrict__ ebuf) {
    __shared__ int loff[NBUCK];
    int blk = blockIdx.x, t = threadIdx.x;
    for (int i = t; i < NBUCK; i += 256) loff[i] = table[i * NBLK_SC + blk];
    __syncthreads();
    int e0 = blk * CHUNK, e1 = e0 + CHUNK;
    for (int e = e0 + t; e < e1; e += 256) {
        int s = eidx[e];
        int d = eidx[E_EDGES + e];
        int p = atomicAdd(&loff[d >> 7], 1);
        ebuf[p] = ((unsigned int)(d & 127) << 17) | (unsigned int)s;
    }
}

__global__ __launch_bounds__(256) void k_bucket(const unsigned int* __restrict__ ebuf,
                                                const int* __restrict__ bucketBase,
                                                int* __restrict__ rowptr,
                                                float* __restrict__ dinv,
                                                int* __restrict__ col) {
    __shared__ int scnt[128], soff[128], scur[128];
    int b = blockIdx.x, t = threadIdx.x;
    int bbase = bucketBase[b], bend = bucketBase[b + 1];
    if (t < 128) { scnt[t] = 0; scur[t] = 0; }
    __syncthreads();
    for (int e = bbase + t; e < bend; e += 256) {
        unsigned int rec = ebuf[e];
        atomicAdd(&scnt[rec >> 17], 1);
    }
    __syncthreads();
    if (t < 128) soff[t] = scnt[t];
    __syncthreads();
    for (int st = 1; st < 128; st <<= 1) {
        int a = (t < 128 && t >= st) ? soff[t - st] : 0;
        __syncthreads();
        if (t < 128) soff[t] += a;
        __syncthreads();
    }
    if (t < 128) {
        int ex = soff[t] - scnt[t];
        int node = b * 128 + t;
        if (node < N_NODES) {
            rowptr[node] = bbase + ex;
            dinv[node] = rsqrtf((float)(scnt[t] + 1));   // +1 self-loop
        }
        soff[t] = ex;
    }
    __syncthreads();
    for (int e = bbase + t; e < bend; e += 256) {
        unsigned int rec = ebuf[e];
        int dl = rec >> 17;
        int s = rec & 0x1FFFF;
        int p = bbase + soff[dl] + atomicAdd(&scur[dl], 1);
        col[p] = s;
    }
}

// ---------------- fused layer 1: g1 = bf16(relu((A' x) W1 + b1)) ----------------

__global__ __launch_bounds__(256) void k_l1(const float* __restrict__ x,
                                            const float* __restrict__ W1,
                                            const float* __restrict__ b1,
                                            const int* __restrict__ rowptr,
                                            const int* __restrict__ col,
                                            const float* __restrict__ dinv,
                                            unsigned int* __restrict__ g1) {
    __shared__ float axs[32][8];       // 32 nodes x 7 feats (+pad)
    __shared__ float w1s[FIN * HID];   // 3.5 KB
    __shared__ float b1s[HID];
    int t = threadIdx.x;
    for (int i = t; i < FIN * HID; i += 256) w1s[i] = W1[i];
    if (t < HID) b1s[t] = b1[t];

    int lane = t & 63, wave = t >> 6;
    int sub = lane >> 3, f = lane & 7;          // node-subgroup, lane role
    int node = blockIdx.x * 32 + wave * 8 + sub;
    bool valid = node < N_NODES;
    float di = valid ? dinv[node] : 0.f;
    float a = (valid && f < 7) ? di * x[node * FIN + f] : 0.f;
    int e0 = valid ? rowptr[node] : 0;
    int e1 = valid ? rowptr[node + 1] : 0;
    for (int base = e0; base < e1; base += 8) {
        int mm = e1 - base; if (mm > 8) mm = 8;
        int sc = (f < mm) ? col[base + f] : 0;
        for (int j = 0; j < mm; ++j) {
            int s = __shfl(sc, sub * 8 + j);
            float v = (f < 7) ? x[s * FIN + f] : dinv[s];
            float ds = __shfl(v, sub * 8 + 7);
            if (f < 7) a += ds * v;
        }
    }
    axs[wave * 8 + sub][f] = (f < 7) ? di * a : 0.f;
    __syncthreads();

    int nl = t >> 3, fb = t & 7;
    int gnode = blockIdx.x * 32 + nl;
    if (gnode < N_NODES) {
        float av[FIN];
        #pragma unroll
        for (int k = 0; k < FIN; ++k) av[k] = axs[nl][k];
        unsigned int outp[8];
        #pragma unroll
        for (int p = 0; p < 8; ++p) {
            int fo = fb * 16 + p * 2;
            float acc0 = b1s[fo], acc1 = b1s[fo + 1];
            #pragma unroll
            for (int k = 0; k < FIN; ++k) {
                acc0 += av[k] * w1s[k * HID + fo];
                acc1 += av[k] * w1s[k * HID + fo + 1];
            }
            outp[p] = pack_bf2(fmaxf(acc0, 0.f), fmaxf(acc1, 0.f));
        }
        *(uint4*)&g1[(size_t)gnode * 64 + fb * 8] = *(uint4*)&outp[0];
        *(uint4*)&g1[(size_t)gnode * 64 + fb * 8 + 4] = *(uint4*)&outp[4];
    }
}

// ---------------- 128-wide aggregation (wave/node, bf16 gather, shfl-batched) --------

__global__ void k_agg128(const unsigned int* __restrict__ g,   // packed bf16 pairs [N][64]
                         unsigned int* __restrict__ oB,
                         const int* __restrict__ rowptr, const int* __restrict__ col,
                         const float* __restrict__ dinv) {
    int wid = (blockIdx.x * blockDim.x + threadIdx.x) >> 6;
    int lane = threadIdx.x & 63;
    if (wid >= N_NODES) return;
    int i = wid;
    float di = dinv[i];
    unsigned int v = g[(size_t)i * 64 + lane];
    float ax = di * bf_lo(v), ay = di * bf_hi(v);
    int e0 = rowptr[i], e1 = rowptr[i + 1];
    for (int base = e0; base < e1; base += 64) {
        int m = e1 - base; if (m > 64) m = 64;
        int sc = 0; float dsv = 0.f;
        if (lane < m) { sc = col[base + lane]; dsv = dinv[sc]; }
        int j = 0;
        for (; j + 7 < m; j += 8) {
            int s0 = __shfl(sc, j),     s1 = __shfl(sc, j + 1);
            int s2 = __shfl(sc, j + 2), s3 = __shfl(sc, j + 3);
            int s4 = __shfl(sc, j + 4), s5 = __shfl(sc, j + 5);
            int s6 = __shfl(sc, j + 6), s7 = __shfl(sc, j + 7);
            float d0 = __shfl(dsv, j),     d1 = __shfl(dsv, j + 1);
            float d2 = __shfl(dsv, j + 2), d3 = __shfl(dsv, j + 3);
            float d4 = __shfl(dsv, j + 4), d5 = __shfl(dsv, j + 5);
            float d6 = __shfl(dsv, j + 6), d7 = __shfl(dsv, j + 7);
            unsigned int u0 = g[(size_t)s0 * 64 + lane];
            unsigned int u1 = g[(size_t)s1 * 64 + lane];
            unsigned int u2 = g[(size_t)s2 * 64 + lane];
            unsigned int u3 = g[(size_t)s3 * 64 + lane];
            unsigned int u4 = g[(size_t)s4 * 64 + lane];
            unsigned int u5 = g[(size_t)s5 * 64 + lane];
            unsigned int u6 = g[(size_t)s6 * 64 + lane];
            unsigned int u7 = g[(size_t)s7 * 64 + lane];
            ax += d0 * bf_lo(u0); ay += d0 * bf_hi(u0);
            ax += d1 * bf_lo(u1); ay += d1 * bf_hi(u1);
            ax += d2 * bf_lo(u2); ay += d2 * bf_hi(u2);
            ax += d3 * bf_lo(u3); ay += d3 * bf_hi(u3);
            ax += d4 * bf_lo(u4); ay += d4 * bf_hi(u4);
            ax += d5 * bf_lo(u5); ay += d5 * bf_hi(u5);
            ax += d6 * bf_lo(u6); ay += d6 * bf_hi(u6);
            ax += d7 * bf_lo(u7); ay += d7 * bf_hi(u7);
        }
        for (; j + 3 < m; j += 4) {
            int s0 = __shfl(sc, j),     s1 = __shfl(sc, j + 1);
            int s2 = __shfl(sc, j + 2), s3 = __shfl(sc, j + 3);
            float d0 = __shfl(dsv, j),     d1 = __shfl(dsv, j + 1);
            float d2 = __shfl(dsv, j + 2), d3 = __shfl(dsv, j + 3);
            unsigned int u0 = g[(size_t)s0 * 64 + lane];
            unsigned int u1 = g[(size_t)s1 * 64 + lane];
            unsigned int u2 = g[(size_t)s2 * 64 + lane];
            unsigned int u3 = g[(size_t)s3 * 64 + lane];
            ax += d0 * bf_lo(u0); ay += d0 * bf_hi(u0);
            ax += d1 * bf_lo(u1); ay += d1 * bf_hi(u1);
            ax += d2 * bf_lo(u2); ay += d2 * bf_hi(u2);
            ax += d3 * bf_lo(u3); ay += d3 * bf_hi(u3);
        }
        for (; j < m; ++j) {
            int s0 = __shfl(sc, j);
            float d0 = __shfl(dsv, j);
            unsigned int u0 = g[(size_t)s0 * 64 + lane];
            ax += d0 * bf_lo(u0); ay += d0 * bf_hi(u0);
        }
    }
    oB[(size_t)i * 64 + lane] = pack_bf2(di * ax, di * ay);
}

// ---------------- MFMA matmul (layers 2,3): g_out = bf16(relu(A @ WT^T + b)) ---------
// WTg: pre-transposed bf16 weights [n][k] (n-major). Staged to LDS stride 136.

__global__ __launch_bounds__(256) void k_mmx(const unsigned int* __restrict__ gIn,
                                             const unsigned short* __restrict__ WTg,
                                             const float* __restrict__ bias,
                                             unsigned int* __restrict__ outg) {
    __shared__ unsigned short sbuf[128 * 136];   // WT (stride 136), reused as Cs (stride 132)
    int t = threadIdx.x;
    // coalesced copy: 16384 shorts, 8 per thread per iter (uint4)
    for (int i = t * 8; i < 128 * 128; i += 256 * 8) {
        int n = i >> 7, k = i & 127;
        uint4 val = *(const uint4*)(WTg + i);
        *(uint4*)(sbuf + n * 136 + k) = val;
    }

    int lane = t & 63, wave = t >> 6;
    int m = lane & 15, quad = lane >> 4;
    int nodeBase = blockIdx.x * 128 + wave * 32;
    const short* gs = (const short*)gIn;

    float bi[8];
    #pragma unroll
    for (int nt = 0; nt < 8; ++nt) bi[nt] = bias[nt * 16 + m];

    f32x4 acc[2][8];
    #pragma unroll
    for (int gi = 0; gi < 2; ++gi)
        #pragma unroll
        for (int nt = 0; nt < 8; ++nt)
            acc[gi][nt] = (f32x4){0.f, 0.f, 0.f, 0.f};

    __syncthreads();

    #pragma unroll
    for (int kc = 0; kc < 4; ++kc) {
        bf16x8 ah[2];
        #pragma unroll
        for (int gi = 0; gi < 2; ++gi) {
            int node = nodeBase + gi * 16 + m;
            bf16x8 h = {0, 0, 0, 0, 0, 0, 0, 0};
            if (node < N_NODES)
                h = *(const bf16x8*)(gs + (size_t)node * 128 + kc * 32 + quad * 8);
            ah[gi] = h;
        }
        #pragma unroll
        for (int nt = 0; nt < 8; ++nt) {
            bf16x8 b = *(const bf16x8*)(sbuf + (nt * 16 + m) * 136 + kc * 32 + quad * 8);
            #pragma unroll
            for (int gi = 0; gi < 2; ++gi)
                acc[gi][nt] = __builtin_amdgcn_mfma_f32_16x16x32_bf16(ah[gi], b, acc[gi][nt], 0, 0, 0);
        }
    }

    __syncthreads();
    #pragma unroll
    for (int gi = 0; gi < 2; ++gi)
        #pragma unroll
        for (int nt = 0; nt < 8; ++nt)
            #pragma unroll
            for (int r = 0; r < 4; ++r) {
                int nl = wave * 32 + gi * 16 + quad * 4 + r;
                float vv = acc[gi][nt][r] + bi[nt];
                sbuf[nl * 132 + nt * 16 + m] = (unsigned short)f2bf_rne(fmaxf(vv, 0.f));
            }
    __syncthreads();
    for (int i = t; i < 128 * 32; i += 256) {
        int nl = i >> 5, p = i & 31;
        int node = blockIdx.x * 128 + nl;
        if (node < N_NODES) {
            uint2 val = *(const uint2*)(sbuf + nl * 132 + p * 4);
            *(uint2*)&outg[(size_t)node * 64 + p * 2] = val;
        }
    }
}

// ---------------- pool stage 1: per-chunk partial sums (bf16 in, fp32 atomics) -------

__global__ __launch_bounds__(256) void k_poolsum(const unsigned int* __restrict__ aggB,
                                                 const int* __restrict__ batch,
                                                 float* __restrict__ pooled) {
    int wid = (blockIdx.x * blockDim.x + threadIdx.x) >> 6;   // wave id: 16 nodes each
    int lane = threadIdx.x & 63;
    int n0 = wid * 16;
    if (n0 >= N_NODES) return;
    int n1 = n0 + 16; if (n1 > N_NODES) n1 = N_NODES;
    int curg = batch[n0];
    float ax = 0.f, ay = 0.f;
    for (int n = n0; n < n1; ++n) {
        int g = batch[n];
        if (g != curg) {
            atomicAdd(&pooled[curg * HID + 2 * lane], ax);
            atomicAdd(&pooled[curg * HID + 2 * lane + 1], ay);
            ax = 0.f; ay = 0.f; curg = g;
        }
        unsigned int u = aggB[(size_t)n * 64 + lane];
        ax += bf_lo(u); ay += bf_hi(u);
    }
    atomicAdd(&pooled[curg * HID + 2 * lane], ax);
    atomicAdd(&pooled[curg * HID + 2 * lane + 1], ay);
}

// ---------------- head: mean + fused W4*Wlin linear ----------------

__global__ void k_head(const float* __restrict__ pooled, const int* __restrict__ batch,
                       const float* __restrict__ Wc, const float* __restrict__ bc,
                       const float* __restrict__ blin, float* __restrict__ out) {
    int wid = (blockIdx.x * blockDim.x + threadIdx.x) >> 6;
    int lane = threadIdx.x & 63;
    if (wid >= NG) return;
    int g = wid;
    int lo = 0, hi = N_NODES;
    while (lo < hi) { int mid = (lo + hi) >> 1; if (batch[mid] < g) lo = mid + 1; else hi = mid; }
    int start = lo;
    hi = N_NODES;
    while (lo < hi) { int mid = (lo + hi) >> 1; if (batch[mid] < g + 1) lo = mid + 1; else hi = mid; }
    int cnt = lo - start;
    float invc = (cnt > 0) ? 1.0f / (float)cnt : 0.f;
    float px = pooled[g * HID + 2 * lane] * invc;
    float py = pooled[g * HID + 2 * lane + 1] * invc;

    #pragma unroll
    for (int o = 0; o < 2; ++o) {
        float v = px * Wc[(2 * lane) * 2 + o] + py * Wc[(2 * lane + 1) * 2 + o];
        #pragma unroll
        for (int s = 32; s > 0; s >>= 1) v += __shfl_down(v, s);
        if (lane == 0) out[g * 2 + o] = (cnt > 0) ? (v + bc[o]) : blin[o];
    }
}

// ---------------- launcher ----------------

extern "C" void kernel_launch(void* const* d_in, const int* in_sizes, int n_in,
                              void* d_out, int out_size, void* d_ws, size_t ws_size,
                              hipStream_t stream) {
    const float* x    = (const float*)d_in[0];
    const int*   eidx = (const int*)d_in[1];
    const int*   batch= (const int*)d_in[2];
    const float* W1   = (const float*)d_in[3];
    const float* b1   = (const float*)d_in[4];
    const float* W2   = (const float*)d_in[5];
    const float* b2   = (const float*)d_in[6];
    const float* W3   = (const float*)d_in[7];
    const float* b3   = (const float*)d_in[8];
    const float* W4   = (const float*)d_in[9];
    const float* b4   = (const float*)d_in[10];
    const float* Wlin = (const float*)d_in[11];
    const float* blin = (const float*)d_in[12];
    float* out = (float*)d_out;

    // workspace carve-up (256B aligned)
    char* ws = (char*)d_ws;
    size_t off = 0;
    auto carve = [&](size_t bytes) { char* p = ws + off; off = (off + bytes + 255) & ~(size_t)255; return p; };
    int*   rowptr    = (int*)carve((size_t)(N_NODES + 1) * 4);
    float* dinv      = (float*)carve((size_t)N_NODES * 4);
    int*   col       = (int*)carve((size_t)E_EDGES * 4);
    unsigned int* ebuf = (unsigned int*)carve((size_t)E_EDGES * 4);
    int*   table     = (int*)carve((size_t)TLEN * 4);
    int*   partial   = (int*)carve((size_t)NCH * 4);
    int*   bucketBase= (int*)carve((size_t)(NBUCK + 1) * 4);
    unsigned int* gA = (unsigned int*)carve((size_t)N_NODES * 64 * 4);   // 25.6 MB bf16 buffer
    unsigned int* gB = (unsigned int*)carve((size_t)N_NODES * 64 * 4);   // 25.6 MB bf16 buffer
    float* pooled    = (float*)carve((size_t)NG * HID * 4);
    float* Wc        = (float*)carve((size_t)HID * 2 * 4);
    float* bc        = (float*)carve(2 * 4);
    unsigned short* WT2 = (unsigned short*)carve((size_t)HID * HID * 2);
    unsigned short* WT3 = (unsigned short*)carve((size_t)HID * HID * 2);
    (void)ws_size; (void)n_in; (void)in_sizes; (void)out_size;

    const int BLK = 256;
    int gridAgg = (N_NODES * 64 + BLK - 1) / BLK;
    int gridL1 = (N_NODES + 31) / 32;               // 3125
    int gridPS = ((N_NODES + 15) / 16 * 64 + BLK - 1) / BLK;
    int gridHead = (NG * 64 + BLK - 1) / BLK;

    // CSR hist + pooled zero + Wc fold + WT2/WT3 conversion (single fused dispatch)
    k_hist2<<<NBLK_SC + 193, BLK, 0, stream>>>(eidx, table, W4, b4, Wlin, blin,
                                               Wc, bc, pooled, W2, W3, WT2, WT3);
    k_blocksum<<<NCH, BLK, 0, stream>>>(table, partial);
    k_scan_blk<<<1, 256, 0, stream>>>(partial, bucketBase, rowptr);
    k_scan_final<<<NCH, 1024, 0, stream>>>(table, partial, bucketBase);
    k_scatter2<<<NBLK_SC, BLK, 0, stream>>>(eidx, table, ebuf);
    k_bucket<<<NBUCK, BLK, 0, stream>>>(ebuf, bucketBase, rowptr, dinv, col);

    // layer 1 (fused agg + matmul)
    k_l1<<<gridL1, BLK, 0, stream>>>(x, W1, b1, rowptr, col, dinv, gA);

    // layer 2: a2 = bf16(A' g1) -> MFMA mm -> g2
    k_agg128<<<gridAgg, BLK, 0, stream>>>(gA, gB, rowptr, col, dinv);
    k_mmx<<<MMX_GRID, BLK, 0, stream>>>(gB, WT2, b2, gA);
    // layer 3: a3 = bf16(A' g2) -> MFMA mm -> g3
    k_agg128<<<gridAgg, BLK, 0, stream>>>(gA, gB, rowptr, col, dinv);
    k_mmx<<<MMX_GRID, BLK, 0, stream>>>(gB, WT3, b3, gA);
    // layer 4: aggregation only (W4 folded into head), bf16 out
    k_agg128<<<gridAgg, BLK, 0, stream>>>(gA, gB, rowptr, col, dinv);

    // pool + head
    k_poolsum<<<gridPS, BLK, 0, stream>>>(gB, batch, pooled);
    k_head<<<gridHead, BLK, 0, stream>>>(pooled, batch, Wc, bc, blin, out);
}